// Round 16
// baseline (91.291 us; speedup 1.0000x reference)
//
#include <hip/hip_runtime.h>
#include <hip/hip_bf16.h>

// ChebyKANLinear: y[b,j] = sum_i sum_k T_k(tanh(x[b,i])) * C[i,j,k]
// GEMM: M=16384, N=512, K=4608 (kflat = k*512 + i), k=0 folded into S0[j].
// v15 = v14 (XCD-parity N-split -> W2 half L2-resident; interleaved
//   produce/consume; 4-set depth-3 B prefetch; 1 barrier/ic) +
//   (a) 32x32x16 MFMA: 4060 vs 3378 FLOP/cyc (-17% matrix time) and half
//       the MFMA issue slots. Wave tile 64x32 = 2 tiles of 32x32 x 2 k-subs.
//       C/D layout (m74/m101-verified): col=lane&31, row=(reg&3)+8(reg>>2)
//       +4(lane>>5). A/B: row/col=lane&31, k=(lane>>5)*8+e.
//   (b) T5 s_setprio(1) around the MFMA cluster (waves are role-staggered).

typedef __bf16 bf16x8 __attribute__((ext_vector_type(8)));
typedef __bf16 bf16x4 __attribute__((ext_vector_type(4)));
typedef float  f32x4  __attribute__((ext_vector_type(4)));
typedef float  f32x16 __attribute__((ext_vector_type(16)));

#define DIM  512
#define KDEG 9
#define NK   8               // k = 1..8 (k=0 folded into S0)
#define NIC  16
#define SLAB (4 * DIM * 8)   // 16384 bf16 per (k,ic) slab of W2

// ---- pack: C[i][j][k] -> W2[(k*16+ic)][s][j][e] (bf16), i = ic*32 + s*8 + e ----
__global__ void pack_w_kernel(const float* __restrict__ coeffs,
                              __bf16* __restrict__ W2) {
    int t  = blockIdx.x * blockDim.x + threadIdx.x;   // 32768 threads
    int j  = t & (DIM - 1);
    int s  = (t >> 9) & 3;
    int ic = t >> 11;

    bf16x8 v[KDEG];
#pragma unroll
    for (int e = 0; e < 8; ++e) {
        int i = ic * 32 + s * 8 + e;
        const float* src = coeffs + ((size_t)i * DIM + j) * KDEG;
#pragma unroll
        for (int k = 0; k < KDEG; ++k)
            v[k][e] = (__bf16)src[k];
    }
#pragma unroll
    for (int k = 0; k < KDEG; ++k) {
        size_t off = (size_t)(k * 16 + ic) * SLAB + ((size_t)s * DIM + j) * 8;
        *reinterpret_cast<bf16x8*>(W2 + off) = v[k];
    }
}

// ---- S0[j] = sum_i C[i][j][0] (f32) into W2's k=0 slab (GEMM never reads it) ----
__global__ void s0_kernel(const float* __restrict__ coeffs,
                          float* __restrict__ S0) {
    const int j    = blockIdx.x;      // 512 blocks
    const int lane = threadIdx.x;     // 64
    float s = 0.0f;
#pragma unroll
    for (int i = lane; i < DIM; i += 64)
        s += coeffs[((size_t)i * DIM + j) * KDEG];
#pragma unroll
    for (int off = 32; off > 0; off >>= 1)
        s += __shfl_down(s, off, 64);
    if (lane == 0) S0[j] = s;
}

// ---------------- fused GEMM: consume(ic) with produce(ic+1) interleaved --------
__global__ __launch_bounds__(512, 4) void cheby_gemm_kernel(
    const float* __restrict__ x,
    const __bf16* __restrict__ W2,
    float* __restrict__ out)
{
    // double-buffered A-tile: [buf][kk][row(64)][slot(4)][8] bf16, 2 x 32KB
    __shared__ __bf16 A_lds[2][NK][64][4][8];

    const int tid   = threadIdx.x;
    const int lane  = tid & 63;
    const int wid   = tid >> 6;      // 0..7 = n-group (32 cols each)
    const int l31   = lane & 31;
    const int h     = lane >> 5;     // 0..1 (k-half within MFMA)
    const int nhalf = blockIdx.x & 1;            // == XCD parity (XCD = bid%8)
    const int bm    = (blockIdx.x >> 1) * 64;
    const int cb    = nhalf * 256 + wid * 32;    // wave's column base

    // ---- producer mapping (v12-verified): thread owns 4 consecutive i ----
    const int prow  = tid >> 3;           // 0..63
    const int pi4   = (tid & 7) * 4;      // 0,4,...,28
    const int pslot = pi4 >> 3;           // 0..3
    const int phalf = (pi4 >> 2) & 1;     // 8B half within slot
    const int rsw   = (prow >> 1) & 3;    // row-pair slot swizzle
    __bf16* wp = &A_lds[0][0][prow][pslot ^ rsw][phalf * 4];
    const float* xp = x + (size_t)(bm + prow) * DIM + pi4;

    // ---- consumer A: row = mf*32 + l31; logical slot = ksub*2 + h ----
    // rsw depends only on l31 (mf*32>>1 = 16mf ≡ 0 mod 4)
    const int rswc = (l31 >> 1) & 3;
    // element offset of A_lds[buf][kk][row][slot][0] = ((buf*8+kk)*64+row)*32 + slot*8
    const __bf16* abase = &A_lds[0][0][l31][0][0];

    // ---- B lane base: granule ((ksub*2+h)*DIM + cb + l31), 16B each ----
    const __bf16* wbase = W2 + ((size_t)h * DIM + cb + l31) * 8;

    // acc init from S0 (the k=0 term): every row of col gets S0[col]
    const float* S0 = (const float*)W2;
    f32x16 acc[2];
    {
        float s0v = S0[cb + l31];
#pragma unroll
        for (int mf = 0; mf < 2; ++mf)
#pragma unroll
            for (int r = 0; r < 16; ++r)
                acc[mf][r] = s0v;
    }

    // ================= prologue =================
    // x(0); produce ic=0 into buf 0 (serial, once)
    f32x4 xq = *reinterpret_cast<const f32x4*>(xp);
    {
        float Tk[4], Tm[4], t2[4];
#pragma unroll
        for (int e = 0; e < 4; ++e) {
            float p = __builtin_amdgcn_exp2f(xq[e] * 2.8853900817779268f);
            float t = 1.0f - 2.0f * __builtin_amdgcn_rcpf(p + 1.0f);
            Tk[e] = t;  t2[e] = t + t;  Tm[e] = 1.0f;
        }
#pragma unroll
        for (int kk = 0; kk < NK; ++kk) {
            bf16x4 v;
#pragma unroll
            for (int e = 0; e < 4; ++e) v[e] = (__bf16)Tk[e];
            *reinterpret_cast<bf16x4*>(wp + kk * 2048) = v;
            if (kk < NK - 1) {
#pragma unroll
                for (int e = 0; e < 4; ++e) {
                    float Tn = __builtin_fmaf(t2[e], Tk[e], -Tm[e]);
                    Tm[e] = Tk[e];  Tk[e] = Tn;
                }
            }
        }
    }
    // x(1) for the first interleaved produce
    xq = *reinterpret_cast<const f32x4*>(xp + 32);

    // B prologue: sets 0,1,2 = slabs (k=1..3, ic=0); bq[set][ksub]
    bf16x8 bq[4][2];
#pragma unroll
    for (int s = 0; s < 3; ++s)
#pragma unroll
        for (int ks = 0; ks < 2; ++ks)
            bq[s][ks] = *reinterpret_cast<const bf16x8*>(
                wbase + (size_t)((s + 1) * 16) * SLAB + ks * 8192);

    asm volatile("s_waitcnt lgkmcnt(0)" ::: "memory");
    __builtin_amdgcn_s_barrier();

    // produce-state registers (live across ksteps within one body)
    float Tk[4], Tm[4], t2[4];

    // BODY: consume ic from buf BUF; optionally produce ic+1 into buf 1-BUF.
#define BODY(BUF, IC, PROD, XLOAD, PREFX)                                        \
    {                                                                            \
        _Pragma("unroll")                                                        \
        for (int k = 1; k <= NK; ++k) {                                          \
            /* B prefetch, 3 ksteps ahead, into set (k+2)&3 */                   \
            if (k <= 5 || PREFX) {                                               \
                const int nk  = (k <= 5) ? k + 3 : k - 5;                        \
                const int nic = (k <= 5) ? (IC) : (IC) + 1;                      \
                const __bf16* np = wbase + (size_t)(nk * 16 + nic) * SLAB;       \
                _Pragma("unroll")                                                \
                for (int ks = 0; ks < 2; ++ks)                                   \
                    bq[(k + 2) & 3][ks] =                                        \
                        *reinterpret_cast<const bf16x8*>(np + ks * 8192);        \
            }                                                                    \
            /* A frags from LDS: af[mf][ksub], slot (ksub*2+h)^rswc */           \
            bf16x8 af[2][2];                                                     \
            _Pragma("unroll")                                                    \
            for (int mf = 0; mf < 2; ++mf)                                       \
                _Pragma("unroll")                                                \
                for (int ks = 0; ks < 2; ++ks)                                   \
                    af[mf][ks] = *reinterpret_cast<const bf16x8*>(               \
                        abase + (BUF) * 16384 + (k - 1) * 2048 +                 \
                        mf * 32 * 32 + (((ks * 2 + h) ^ rswc) * 8));             \
            /* 4 MFMA 32x32x16 on set (k-1)&3 */                                 \
            __builtin_amdgcn_s_setprio(1);                                       \
            _Pragma("unroll")                                                    \
            for (int mf = 0; mf < 2; ++mf)                                       \
                _Pragma("unroll")                                                \
                for (int ks = 0; ks < 2; ++ks)                                   \
                    acc[mf] = __builtin_amdgcn_mfma_f32_32x32x16_bf16(           \
                        af[mf][ks], bq[(k - 1) & 3][ks], acc[mf], 0, 0, 0);      \
            __builtin_amdgcn_s_setprio(0);                                       \
            /* interleaved produce of ic+1 into the other buffer */              \
            if (PROD) {                                                          \
                if (k == 1) {                                                    \
                    _Pragma("unroll")                                            \
                    for (int e = 0; e < 4; ++e) {                                \
                        float p = __builtin_amdgcn_exp2f(                        \
                            xq[e] * 2.8853900817779268f);                        \
                        float t = 1.0f - 2.0f * __builtin_amdgcn_rcpf(p + 1.0f); \
                        Tk[e] = t;  t2[e] = t + t;  Tm[e] = 1.0f;                \
                    }                                                            \
                } else {                                                         \
                    _Pragma("unroll")                                            \
                    for (int e = 0; e < 4; ++e) {                                \
                        float Tn = __builtin_fmaf(t2[e], Tk[e], -Tm[e]);         \
                        Tm[e] = Tk[e];  Tk[e] = Tn;                              \
                    }                                                            \
                }                                                                \
                bf16x4 v;                                                        \
                _Pragma("unroll")                                                \
                for (int e = 0; e < 4; ++e) v[e] = (__bf16)Tk[e];                \
                *reinterpret_cast<bf16x4*>(                                      \
                    wp + (1 - (BUF)) * 16384 + (k - 1) * 2048) = v;              \
            }                                                                    \
            if (XLOAD && k == 2)                                                 \
                xq = *reinterpret_cast<const f32x4*>(xp + ((IC) + 2) * 32);      \
        }                                                                        \
        if (PROD) {                                                              \
            asm volatile("s_waitcnt lgkmcnt(0)" ::: "memory");                   \
            __builtin_amdgcn_s_barrier();                                        \
        }                                                                        \
    }

    // main: ic = 0..13 (full pipeline; x(ic+2) <= x(15) always valid)
    for (int icp = 0; icp < 14; icp += 2) {
        BODY(0, icp,     1, 1, 1);
        BODY(1, icp + 1, 1, 1, 1);
    }
    // tail: ic=14 (produce 15, no x-load), ic=15 (drain)
    BODY(0, 14, 1, 0, 1);
    BODY(1, 15, 0, 0, 0);
#undef BODY

    // ---- epilogue: 32x32 C/D layout col=lane&31, row=(r&3)+8*(r>>2)+4*h ----
#pragma unroll
    for (int mf = 0; mf < 2; ++mf)
#pragma unroll
        for (int r = 0; r < 16; ++r) {
            const int row = bm + mf * 32 + (r & 3) + 8 * (r >> 2) + 4 * h;
            out[(size_t)row * DIM + cb + l31] = acc[mf][r];
        }
}

extern "C" void kernel_launch(void* const* d_in, const int* in_sizes, int n_in,
                              void* d_out, int out_size, void* d_ws, size_t ws_size,
                              hipStream_t stream) {
    const float* x      = (const float*)d_in[0];   // (16384, 512)
    const float* coeffs = (const float*)d_in[1];   // (512, 512, 9)
    float* out          = (float*)d_out;           // (16384, 512)
    __bf16* W2          = (__bf16*)d_ws;           // 144*16384 bf16 = 4.7MB

    pack_w_kernel<<<(DIM * 64) / 256, 256, 0, stream>>>(coeffs, W2);
    s0_kernel<<<DIM, 64, 0, stream>>>(coeffs, (float*)W2);

    // grid = 2 n-halves x 256 m-blocks = 512 blocks of 512 thr = 2 blocks/CU
    // = 4 waves/SIMD. nhalf = bid&1 matches XCD parity (XCD = bid%8) -> each
    // XCD L2 holds one 2.36MB W2 half, fully resident.
    cheby_gemm_kernel<<<512, 512, 0, stream>>>(x, W2, out);
}

// Round 17
// 77.114 us; speedup vs baseline: 1.1838x; 1.1838x over previous
//
#include <hip/hip_runtime.h>
#include <hip/hip_bf16.h>

// ChebyKANLinear: y[b,j] = sum_i sum_k T_k(tanh(x[b,i])) * C[i,j,k]
// GEMM: M=16384, N=512, K=4608 (kflat = k*512 + i), k=0 folded into S0[j].
// v16 = v14's interleaved produce/consume BODY + balanced 64x64 wave tile:
//   v14 was A-LDS-BOUND (16 waves x 4 ds_read_b128 x 12cyc = 768 cyc/kstep
//   > 620 matrix). W_N 32->64 halves A-LDS traffic (46->23us, under the 37us
//   matrix floor); W_M=64 keeps B-L1 at 52 B/cyc. 256-thr 4-wave blocks
//   (1m x 4n), BM=64, BN=256 XCD-parity, 2 blocks/CU (anti-phased produce/
//   consume; B L2-resident so 2 waves/SIMD latency is covered). 16x16x32
//   MFMA (zero-conflict verified swizzle; v15's 32x32 hit structural 4-way
//   A-read conflicts, 8.4M). Produce = 8 vals/thread, 1 ds_write_b128/kstep.

typedef __bf16 bf16x8 __attribute__((ext_vector_type(8)));
typedef float  f32x4  __attribute__((ext_vector_type(4)));

#define DIM  512
#define KDEG 9
#define NK   8               // k = 1..8 (k=0 folded into S0)
#define NIC  16
#define SLAB (4 * DIM * 8)   // 16384 bf16 per (k,ic) slab of W2

// ---- pack: C[i][j][k] -> W2[(k*16+ic)][s][j][e] (bf16), i = ic*32 + s*8 + e ----
__global__ void pack_w_kernel(const float* __restrict__ coeffs,
                              __bf16* __restrict__ W2) {
    int t  = blockIdx.x * blockDim.x + threadIdx.x;   // 32768 threads
    int j  = t & (DIM - 1);
    int s  = (t >> 9) & 3;
    int ic = t >> 11;

    bf16x8 v[KDEG];
#pragma unroll
    for (int e = 0; e < 8; ++e) {
        int i = ic * 32 + s * 8 + e;
        const float* src = coeffs + ((size_t)i * DIM + j) * KDEG;
#pragma unroll
        for (int k = 0; k < KDEG; ++k)
            v[k][e] = (__bf16)src[k];
    }
#pragma unroll
    for (int k = 0; k < KDEG; ++k) {
        size_t off = (size_t)(k * 16 + ic) * SLAB + ((size_t)s * DIM + j) * 8;
        *reinterpret_cast<bf16x8*>(W2 + off) = v[k];
    }
}

// ---- S0[j] = sum_i C[i][j][0] (f32) into W2's k=0 slab (GEMM never reads it) ----
__global__ void s0_kernel(const float* __restrict__ coeffs,
                          float* __restrict__ S0) {
    const int j    = blockIdx.x;      // 512 blocks
    const int lane = threadIdx.x;     // 64
    float s = 0.0f;
#pragma unroll
    for (int i = lane; i < DIM; i += 64)
        s += coeffs[((size_t)i * DIM + j) * KDEG];
#pragma unroll
    for (int off = 32; off > 0; off >>= 1)
        s += __shfl_down(s, off, 64);
    if (lane == 0) S0[j] = s;
}

// ---------------- fused GEMM: consume(ic) with produce(ic+1) interleaved --------
__global__ __launch_bounds__(256, 2) void cheby_gemm_kernel(
    const float* __restrict__ x,
    const __bf16* __restrict__ W2,
    float* __restrict__ out)
{
    // double-buffered A-tile: [buf][kk][row(64)][slot(4)][8] bf16, 2 x 32KB
    __shared__ __bf16 A_lds[2][NK][64][4][8];

    const int tid   = threadIdx.x;
    const int lane  = tid & 63;
    const int wid   = tid >> 6;      // 0..3 = n-group (64 cols each)
    const int l15   = lane & 15;
    const int l4    = lane >> 4;     // 0..3
    const int nhalf = blockIdx.x & 1;            // == XCD parity (XCD = bid%8)
    const int bm    = (blockIdx.x >> 1) * 64;
    const int cb    = nhalf * 256 + wid * 64;    // wave's column base

    // ---- producer mapping: thread owns 8 consecutive i (one slot) of a row ----
    const int prow = tid >> 2;            // 0..63
    const int ps   = tid & 3;             // slot 0..3
    const int rsw  = (prow >> 1) & 3;     // row-pair slot swizzle
    __bf16* wp = &A_lds[0][0][prow][ps ^ rsw][0];
    const float* xp = x + (size_t)(bm + prow) * DIM + ps * 8;

    // ---- consumer A read base: row = mf*16 + l15, logical slot l4 ----
    const __bf16* abase = &A_lds[0][0][l15][l4 ^ ((l15 >> 1) & 3)][0];

    // ---- B lane base: granule (l4*DIM + cb + nf*16 + l15), 16B each ----
    const __bf16* wbase = W2 + ((size_t)l4 * DIM + cb + l15) * 8;

    // acc init from S0 (the k=0 term)
    const float* S0 = (const float*)W2;
    f32x4 acc[4][4];
#pragma unroll
    for (int nf = 0; nf < 4; ++nf) {
        float s0v = S0[cb + nf * 16 + l15];
#pragma unroll
        for (int mf = 0; mf < 4; ++mf)
#pragma unroll
            for (int r = 0; r < 4; ++r)
                acc[mf][nf][r] = s0v;
    }

    // ================= prologue =================
    // x(0); produce ic=0 into buf 0 (serial, once)
    f32x4 xqa = *reinterpret_cast<const f32x4*>(xp);
    f32x4 xqb = *reinterpret_cast<const f32x4*>(xp + 4);
    {
        float Tk[8], Tm[8], t2[8];
#pragma unroll
        for (int e = 0; e < 8; ++e) {
            float xv = (e < 4) ? xqa[e] : xqb[e - 4];
            float p = __builtin_amdgcn_exp2f(xv * 2.8853900817779268f);
            float t = 1.0f - 2.0f * __builtin_amdgcn_rcpf(p + 1.0f);
            Tk[e] = t;  t2[e] = t + t;  Tm[e] = 1.0f;
        }
#pragma unroll
        for (int kk = 0; kk < NK; ++kk) {
            bf16x8 v;
#pragma unroll
            for (int e = 0; e < 8; ++e) v[e] = (__bf16)Tk[e];
            *reinterpret_cast<bf16x8*>(wp + kk * 2048) = v;
            if (kk < NK - 1) {
#pragma unroll
                for (int e = 0; e < 8; ++e) {
                    float Tn = __builtin_fmaf(t2[e], Tk[e], -Tm[e]);
                    Tm[e] = Tk[e];  Tk[e] = Tn;
                }
            }
        }
    }
    // x(1) for the first interleaved produce
    xqa = *reinterpret_cast<const f32x4*>(xp + 32);
    xqb = *reinterpret_cast<const f32x4*>(xp + 36);

    // B prologue: sets 0,1,2 = slabs (k=1..3, ic=0)
    bf16x8 bq[4][4];
#pragma unroll
    for (int s = 0; s < 3; ++s)
#pragma unroll
        for (int nf = 0; nf < 4; ++nf)
            bq[s][nf] = *reinterpret_cast<const bf16x8*>(
                wbase + (size_t)((s + 1) * 16) * SLAB + nf * 128);

    asm volatile("s_waitcnt lgkmcnt(0)" ::: "memory");
    __builtin_amdgcn_s_barrier();

    // produce-state registers (live across ksteps within one body)
    float Tk[8], Tm[8], t2[8];

    // BODY: consume ic from buf BUF; optionally produce ic+1 into buf 1-BUF.
#define BODY(BUF, IC, PROD, XLOAD, PREFX)                                        \
    {                                                                            \
        _Pragma("unroll")                                                        \
        for (int k = 1; k <= NK; ++k) {                                          \
            /* B prefetch, 3 ksteps ahead, into set (k+2)&3 */                   \
            if (k <= 5 || PREFX) {                                               \
                const int nk  = (k <= 5) ? k + 3 : k - 5;                        \
                const int nic = (k <= 5) ? (IC) : (IC) + 1;                      \
                const __bf16* np = wbase + (size_t)(nk * 16 + nic) * SLAB;       \
                _Pragma("unroll")                                                \
                for (int nf = 0; nf < 4; ++nf)                                   \
                    bq[(k + 2) & 3][nf] =                                        \
                        *reinterpret_cast<const bf16x8*>(np + nf * 128);         \
            }                                                                    \
            /* A frags from LDS (conflict-free swizzled) */                      \
            bf16x8 af[4];                                                        \
            _Pragma("unroll")                                                    \
            for (int mf = 0; mf < 4; ++mf)                                       \
                af[mf] = *reinterpret_cast<const bf16x8*>(                       \
                    abase + (BUF) * 16384 + (k - 1) * 2048 + mf * 512);          \
            /* 16 MFMA on set (k-1)&3 */                                         \
            __builtin_amdgcn_s_setprio(1);                                       \
            _Pragma("unroll")                                                    \
            for (int nf = 0; nf < 4; ++nf)                                       \
                _Pragma("unroll")                                                \
                for (int mf = 0; mf < 4; ++mf)                                   \
                    acc[mf][nf] = __builtin_amdgcn_mfma_f32_16x16x32_bf16(       \
                        af[mf], bq[(k - 1) & 3][nf], acc[mf][nf], 0, 0, 0);      \
            __builtin_amdgcn_s_setprio(0);                                       \
            /* interleaved produce of ic+1 into the other buffer */              \
            if (PROD) {                                                          \
                if (k == 1) {                                                    \
                    _Pragma("unroll")                                            \
                    for (int e = 0; e < 8; ++e) {                                \
                        float xv = (e < 4) ? xqa[e] : xqb[e - 4];                \
                        float p = __builtin_amdgcn_exp2f(                        \
                            xv * 2.8853900817779268f);                           \
                        float t = 1.0f - 2.0f * __builtin_amdgcn_rcpf(p + 1.0f); \
                        Tk[e] = t;  t2[e] = t + t;  Tm[e] = 1.0f;                \
                    }                                                            \
                } else {                                                         \
                    _Pragma("unroll")                                            \
                    for (int e = 0; e < 8; ++e) {                                \
                        float Tn = __builtin_fmaf(t2[e], Tk[e], -Tm[e]);         \
                        Tm[e] = Tk[e];  Tk[e] = Tn;                              \
                    }                                                            \
                }                                                                \
                bf16x8 v;                                                        \
                _Pragma("unroll")                                                \
                for (int e = 0; e < 8; ++e) v[e] = (__bf16)Tk[e];                \
                *reinterpret_cast<bf16x8*>(                                      \
                    wp + (1 - (BUF)) * 16384 + (k - 1) * 2048) = v;              \
            }                                                                    \
            if (XLOAD && k == 2) {                                               \
                xqa = *reinterpret_cast<const f32x4*>(xp + ((IC) + 2) * 32);     \
                xqb = *reinterpret_cast<const f32x4*>(xp + ((IC) + 2) * 32 + 4); \
            }                                                                    \
        }                                                                        \
        if (PROD) {                                                              \
            asm volatile("s_waitcnt lgkmcnt(0)" ::: "memory");                   \
            __builtin_amdgcn_s_barrier();                                        \
        }                                                                        \
    }

    // main: ic = 0..13 (full pipeline; x(ic+2) <= x(15) always valid)
    for (int icp = 0; icp < 14; icp += 2) {
        BODY(0, icp,     1, 1, 1);
        BODY(1, icp + 1, 1, 1, 1);
    }
    // tail: ic=14 (produce 15, no x-load), ic=15 (drain)
    BODY(0, 14, 1, 0, 1);
    BODY(1, 15, 0, 0, 0);
#undef BODY

    // ---- epilogue: C/D layout col=lane&15, row=(lane>>4)*4+r ----
#pragma unroll
    for (int mf = 0; mf < 4; ++mf)
#pragma unroll
        for (int r = 0; r < 4; ++r) {
            const int row = bm + mf * 16 + l4 * 4 + r;
            float* orow = out + (size_t)row * DIM + cb + l15;
#pragma unroll
            for (int nf = 0; nf < 4; ++nf)
                orow[nf * 16] = acc[mf][nf][r];
        }
}

extern "C" void kernel_launch(void* const* d_in, const int* in_sizes, int n_in,
                              void* d_out, int out_size, void* d_ws, size_t ws_size,
                              hipStream_t stream) {
    const float* x      = (const float*)d_in[0];   // (16384, 512)
    const float* coeffs = (const float*)d_in[1];   // (512, 512, 9)
    float* out          = (float*)d_out;           // (16384, 512)
    __bf16* W2          = (__bf16*)d_ws;           // 144*16384 bf16 = 4.7MB

    pack_w_kernel<<<(DIM * 64) / 256, 256, 0, stream>>>(coeffs, W2);
    s0_kernel<<<DIM, 64, 0, stream>>>(coeffs, (float*)W2);

    // grid = 2 n-halves x 256 m-blocks = 512 blocks of 256 thr = 2 blocks/CU
    // = 8 waves/CU. nhalf = bid&1 == XCD parity -> each XCD L2 holds one
    // 2.36MB W2 half, fully resident. Wave tile 64x64: A-LDS 23us, B-L1 23us,
    // both under the 37us matrix floor.
    cheby_gemm_kernel<<<512, 256, 0, stream>>>(x, W2, out);
}

// Round 18
// 77.068 us; speedup vs baseline: 1.1845x; 1.0006x over previous
//
#include <hip/hip_runtime.h>
#include <hip/hip_bf16.h>

// ChebyKANLinear: y[b,j] = sum_i sum_k T_k(tanh(x[b,i])) * C[i,j,k]
// GEMM: M=16384, N=512, K=4608 (kflat = k*512 + i), k=0 folded into S0[j].
// v17 = v16 (balanced 64x64 wave tile; XCD-parity N-split -> W2 half
//   L2-resident; interleaved produce/consume; depth-3 B reg prefetch;
//   1 barrier/ic; zero-conflict LDS swizzle) + A-FRAGMENT REGISTER DOUBLE
//   BUFFER: ds_read_b128 for kstep k+1 issued before kstep k's MFMA cluster
//   -> the ~120cyc LDS latency (m117) no longer lands on the matrix pipe.
//   (v16 read A-frags just-in-time; compiler does not hoist across ksteps.)

typedef __bf16 bf16x8 __attribute__((ext_vector_type(8)));
typedef float  f32x4  __attribute__((ext_vector_type(4)));

#define DIM  512
#define KDEG 9
#define NK   8               // k = 1..8 (k=0 folded into S0)
#define NIC  16
#define SLAB (4 * DIM * 8)   // 16384 bf16 per (k,ic) slab of W2

// ---- pack: C[i][j][k] -> W2[(k*16+ic)][s][j][e] (bf16), i = ic*32 + s*8 + e ----
__global__ void pack_w_kernel(const float* __restrict__ coeffs,
                              __bf16* __restrict__ W2) {
    int t  = blockIdx.x * blockDim.x + threadIdx.x;   // 32768 threads
    int j  = t & (DIM - 1);
    int s  = (t >> 9) & 3;
    int ic = t >> 11;

    bf16x8 v[KDEG];
#pragma unroll
    for (int e = 0; e < 8; ++e) {
        int i = ic * 32 + s * 8 + e;
        const float* src = coeffs + ((size_t)i * DIM + j) * KDEG;
#pragma unroll
        for (int k = 0; k < KDEG; ++k)
            v[k][e] = (__bf16)src[k];
    }
#pragma unroll
    for (int k = 0; k < KDEG; ++k) {
        size_t off = (size_t)(k * 16 + ic) * SLAB + ((size_t)s * DIM + j) * 8;
        *reinterpret_cast<bf16x8*>(W2 + off) = v[k];
    }
}

// ---- S0[j] = sum_i C[i][j][0] (f32) into W2's k=0 slab (GEMM never reads it) ----
__global__ void s0_kernel(const float* __restrict__ coeffs,
                          float* __restrict__ S0) {
    const int j    = blockIdx.x;      // 512 blocks
    const int lane = threadIdx.x;     // 64
    float s = 0.0f;
#pragma unroll
    for (int i = lane; i < DIM; i += 64)
        s += coeffs[((size_t)i * DIM + j) * KDEG];
#pragma unroll
    for (int off = 32; off > 0; off >>= 1)
        s += __shfl_down(s, off, 64);
    if (lane == 0) S0[j] = s;
}

// ---------------- fused GEMM: consume(ic) with produce(ic+1) interleaved --------
__global__ __launch_bounds__(256, 2) void cheby_gemm_kernel(
    const float* __restrict__ x,
    const __bf16* __restrict__ W2,
    float* __restrict__ out)
{
    // double-buffered A-tile: [buf][kk][row(64)][slot(4)][8] bf16, 2 x 32KB
    __shared__ __bf16 A_lds[2][NK][64][4][8];

    const int tid   = threadIdx.x;
    const int lane  = tid & 63;
    const int wid   = tid >> 6;      // 0..3 = n-group (64 cols each)
    const int l15   = lane & 15;
    const int l4    = lane >> 4;     // 0..3
    const int nhalf = blockIdx.x & 1;            // == XCD parity (XCD = bid%8)
    const int bm    = (blockIdx.x >> 1) * 64;
    const int cb    = nhalf * 256 + wid * 64;    // wave's column base

    // ---- producer mapping: thread owns 8 consecutive i (one slot) of a row ----
    const int prow = tid >> 2;            // 0..63
    const int ps   = tid & 3;             // slot 0..3
    const int rsw  = (prow >> 1) & 3;     // row-pair slot swizzle
    __bf16* wp = &A_lds[0][0][prow][ps ^ rsw][0];
    const float* xp = x + (size_t)(bm + prow) * DIM + ps * 8;

    // ---- consumer A read base: row = mf*16 + l15, logical slot l4 ----
    const __bf16* abase = &A_lds[0][0][l15][l4 ^ ((l15 >> 1) & 3)][0];

    // ---- B lane base: granule (l4*DIM + cb + nf*16 + l15), 16B each ----
    const __bf16* wbase = W2 + ((size_t)l4 * DIM + cb + l15) * 8;

    // acc init from S0 (the k=0 term)
    const float* S0 = (const float*)W2;
    f32x4 acc[4][4];
#pragma unroll
    for (int nf = 0; nf < 4; ++nf) {
        float s0v = S0[cb + nf * 16 + l15];
#pragma unroll
        for (int mf = 0; mf < 4; ++mf)
#pragma unroll
            for (int r = 0; r < 4; ++r)
                acc[mf][nf][r] = s0v;
    }

    // ================= prologue =================
    // x(0); produce ic=0 into buf 0 (serial, once)
    f32x4 xqa = *reinterpret_cast<const f32x4*>(xp);
    f32x4 xqb = *reinterpret_cast<const f32x4*>(xp + 4);
    {
        float Tk[8], Tm[8], t2[8];
#pragma unroll
        for (int e = 0; e < 8; ++e) {
            float xv = (e < 4) ? xqa[e] : xqb[e - 4];
            float p = __builtin_amdgcn_exp2f(xv * 2.8853900817779268f);
            float t = 1.0f - 2.0f * __builtin_amdgcn_rcpf(p + 1.0f);
            Tk[e] = t;  t2[e] = t + t;  Tm[e] = 1.0f;
        }
#pragma unroll
        for (int kk = 0; kk < NK; ++kk) {
            bf16x8 v;
#pragma unroll
            for (int e = 0; e < 8; ++e) v[e] = (__bf16)Tk[e];
            *reinterpret_cast<bf16x8*>(wp + kk * 2048) = v;
            if (kk < NK - 1) {
#pragma unroll
                for (int e = 0; e < 8; ++e) {
                    float Tn = __builtin_fmaf(t2[e], Tk[e], -Tm[e]);
                    Tm[e] = Tk[e];  Tk[e] = Tn;
                }
            }
        }
    }
    // x(1) for the first interleaved produce
    xqa = *reinterpret_cast<const f32x4*>(xp + 32);
    xqb = *reinterpret_cast<const f32x4*>(xp + 36);

    // B prologue: sets 0,1,2 = slabs (k=1..3, ic=0)
    bf16x8 bq[4][4];
#pragma unroll
    for (int s = 0; s < 3; ++s)
#pragma unroll
        for (int nf = 0; nf < 4; ++nf)
            bq[s][nf] = *reinterpret_cast<const bf16x8*>(
                wbase + (size_t)((s + 1) * 16) * SLAB + nf * 128);

    asm volatile("s_waitcnt lgkmcnt(0)" ::: "memory");
    __builtin_amdgcn_s_barrier();

    // produce-state registers (live across ksteps within one body)
    float Tk[8], Tm[8], t2[8];
    // A-fragment register double buffer
    bf16x8 af[2][4];

    // BODY: consume ic from buf BUF; optionally produce ic+1 into buf 1-BUF.
    // A-frag pipeline: set (k-1)&1 holds kstep k's frags; prefetch k+1 into
    // set k&1 BEFORE the MFMA cluster so LDS latency hides under MFMA.
#define BODY(BUF, IC, PROD, XLOAD, PREFX)                                        \
    {                                                                            \
        /* prologue: A-frags for kstep 1 into set 0 */                           \
        _Pragma("unroll")                                                        \
        for (int mf = 0; mf < 4; ++mf)                                           \
            af[0][mf] = *reinterpret_cast<const bf16x8*>(                        \
                abase + (BUF) * 16384 + mf * 512);                               \
        _Pragma("unroll")                                                        \
        for (int k = 1; k <= NK; ++k) {                                          \
            /* A prefetch for kstep k+1 into the other set */                    \
            if (k < NK) {                                                        \
                _Pragma("unroll")                                                \
                for (int mf = 0; mf < 4; ++mf)                                   \
                    af[k & 1][mf] = *reinterpret_cast<const bf16x8*>(            \
                        abase + (BUF) * 16384 + k * 2048 + mf * 512);            \
            }                                                                    \
            /* B prefetch, 3 ksteps ahead, into set (k+2)&3 */                   \
            if (k <= 5 || PREFX) {                                               \
                const int nk  = (k <= 5) ? k + 3 : k - 5;                        \
                const int nic = (k <= 5) ? (IC) : (IC) + 1;                      \
                const __bf16* np = wbase + (size_t)(nk * 16 + nic) * SLAB;       \
                _Pragma("unroll")                                                \
                for (int nf = 0; nf < 4; ++nf)                                   \
                    bq[(k + 2) & 3][nf] =                                        \
                        *reinterpret_cast<const bf16x8*>(np + nf * 128);         \
            }                                                                    \
            /* 16 MFMA on A set (k-1)&1, B set (k-1)&3 */                        \
            __builtin_amdgcn_s_setprio(1);                                       \
            _Pragma("unroll")                                                    \
            for (int nf = 0; nf < 4; ++nf)                                       \
                _Pragma("unroll")                                                \
                for (int mf = 0; mf < 4; ++mf)                                   \
                    acc[mf][nf] = __builtin_amdgcn_mfma_f32_16x16x32_bf16(       \
                        af[(k - 1) & 1][mf], bq[(k - 1) & 3][nf],                \
                        acc[mf][nf], 0, 0, 0);                                   \
            __builtin_amdgcn_s_setprio(0);                                       \
            /* interleaved produce of ic+1 into the other buffer */              \
            if (PROD) {                                                          \
                if (k == 1) {                                                    \
                    _Pragma("unroll")                                            \
                    for (int e = 0; e < 8; ++e) {                                \
                        float xv = (e < 4) ? xqa[e] : xqb[e - 4];                \
                        float p = __builtin_amdgcn_exp2f(                        \
                            xv * 2.8853900817779268f);                           \
                        float t = 1.0f - 2.0f * __builtin_amdgcn_rcpf(p + 1.0f); \
                        Tk[e] = t;  t2[e] = t + t;  Tm[e] = 1.0f;                \
                    }                                                            \
                } else {                                                         \
                    _Pragma("unroll")                                            \
                    for (int e = 0; e < 8; ++e) {                                \
                        float Tn = __builtin_fmaf(t2[e], Tk[e], -Tm[e]);         \
                        Tm[e] = Tk[e];  Tk[e] = Tn;                              \
                    }                                                            \
                }                                                                \
                bf16x8 v;                                                        \
                _Pragma("unroll")                                                \
                for (int e = 0; e < 8; ++e) v[e] = (__bf16)Tk[e];                \
                *reinterpret_cast<bf16x8*>(                                      \
                    wp + (1 - (BUF)) * 16384 + (k - 1) * 2048) = v;              \
            }                                                                    \
            if (XLOAD && k == 2) {                                               \
                xqa = *reinterpret_cast<const f32x4*>(xp + ((IC) + 2) * 32);     \
                xqb = *reinterpret_cast<const f32x4*>(xp + ((IC) + 2) * 32 + 4); \
            }                                                                    \
        }                                                                        \
        if (PROD) {                                                              \
            asm volatile("s_waitcnt lgkmcnt(0)" ::: "memory");                   \
            __builtin_amdgcn_s_barrier();                                        \
        }                                                                        \
    }

    // main: ic = 0..13 (full pipeline; x(ic+2) <= x(15) always valid)
    for (int icp = 0; icp < 14; icp += 2) {
        BODY(0, icp,     1, 1, 1);
        BODY(1, icp + 1, 1, 1, 1);
    }
    // tail: ic=14 (produce 15, no x-load), ic=15 (drain)
    BODY(0, 14, 1, 0, 1);
    BODY(1, 15, 0, 0, 0);
#undef BODY

    // ---- epilogue: C/D layout col=lane&15, row=(lane>>4)*4+r ----
#pragma unroll
    for (int mf = 0; mf < 4; ++mf)
#pragma unroll
        for (int r = 0; r < 4; ++r) {
            const int row = bm + mf * 16 + l4 * 4 + r;
            float* orow = out + (size_t)row * DIM + cb + l15;
#pragma unroll
            for (int nf = 0; nf < 4; ++nf)
                orow[nf * 16] = acc[mf][nf][r];
        }
}

extern "C" void kernel_launch(void* const* d_in, const int* in_sizes, int n_in,
                              void* d_out, int out_size, void* d_ws, size_t ws_size,
                              hipStream_t stream) {
    const float* x      = (const float*)d_in[0];   // (16384, 512)
    const float* coeffs = (const float*)d_in[1];   // (512, 512, 9)
    float* out          = (float*)d_out;           // (16384, 512)
    __bf16* W2          = (__bf16*)d_ws;           // 144*16384 bf16 = 4.7MB

    pack_w_kernel<<<(DIM * 64) / 256, 256, 0, stream>>>(coeffs, W2);
    s0_kernel<<<DIM, 64, 0, stream>>>(coeffs, (float*)W2);

    // grid = 2 n-halves x 256 m-blocks = 512 blocks of 256 thr = 2 blocks/CU
    // = 8 waves/CU. nhalf = bid&1 == XCD parity -> each XCD L2 holds one
    // 2.36MB W2 half, fully resident. Wave tile 64x64: A-LDS 23us, B-L1 23us,
    // both under the 37us matrix floor.
    cheby_gemm_kernel<<<512, 256, 0, stream>>>(x, W2, out);
}